// Round 3
// baseline (489.181 us; speedup 1.0000x reference)
//
#include <hip/hip_runtime.h>
#include <hip/hip_bf16.h>

// B=4, C=96, vol 32^3; HEADS=4, HDIM=24, FOLD=2, PROP=2.
// NCL = 128 cluster batches, each c=24, N=4096 points, M=8 centers.
// Sim/argmax chain computed in float64 to match the numpy reference exactly.

// ---------------- K0: weight transposes (f64 feat weights) ------------------
__global__ __launch_bounds__(256) void k0_prep(
    const float* __restrict__ fw, const float* __restrict__ vw,
    const float* __restrict__ pw, double* __restrict__ wfdT,
    float* __restrict__ wvT, float* __restrict__ wpT)
{
    int t = blockIdx.x * 256 + threadIdx.x;
    if (t < 96 * 96) {
        int o = t / 96, c = t % 96;
        wfdT[c * 96 + o] = (double)fw[o * 96 + c];
        wvT[c * 96 + o]  = vw[o * 96 + c];
        wpT[c * 96 + o]  = pw[o * 96 + c];
    }
}

// ---------------- K1: conv1x1 (feat f64, value bf16) + fold reorder ---------
__global__ __launch_bounds__(256) void k1_conv_fv(
    const float* __restrict__ x, const double* __restrict__ wfdT,
    const float* __restrict__ wvT,
    const float* __restrict__ fb, const float* __restrict__ vb,
    double* __restrict__ feat2, __hip_bfloat16* __restrict__ value2)
{
    __shared__ float xt[96][64];
    const int tile = blockIdx.x;
    const int b = tile >> 9;
    const int s0 = (tile & 511) << 6;
    const float* xb = x + (size_t)b * 96 * 32768;

    #pragma unroll
    for (int k = 0; k < 24; ++k) {
        int idx = k * 256 + threadIdx.x;
        int c = idx >> 6, i = idx & 63;
        xt[c][i] = xb[(size_t)c * 32768 + s0 + i];
    }
    __syncthreads();

    const int i = threadIdx.x & 63;
    const int g = threadIdx.x >> 6;                       // head (wave-uniform)
    const int ob = __builtin_amdgcn_readfirstlane(g * 24);

    double accF[24];
    float  accV[24];
    #pragma unroll
    for (int oo = 0; oo < 24; ++oo) { accF[oo] = (double)fb[ob + oo]; accV[oo] = vb[ob + oo]; }

    for (int c = 0; c < 96; ++c) {
        float xv = xt[c][i];
        double xd = (double)xv;
        const double* wf = wfdT + c * 96 + ob;    // uniform -> s_load
        const float*  wv = wvT  + c * 96 + ob;
        #pragma unroll
        for (int oo = 0; oo < 24; ++oo) {
            accF[oo] = fma(xd, wf[oo], accF[oo]);
            accV[oo] = fmaf(xv, wv[oo], accV[oo]);
        }
    }

    const int s = s0 + i;
    const int D = s & 31, H = (s >> 5) & 31, W = s >> 10;
    const int f1 = W >> 4, f2 = H >> 4, f3 = D >> 4;
    const int n = ((W & 15) << 8) | ((H & 15) << 4) | (D & 15);
    const int B2 = (b << 5) | (g << 3) | (f1 << 2) | (f2 << 1) | f3;
    const size_t base = (size_t)B2 * 24 * 4096 + n;
    #pragma unroll
    for (int oo = 0; oo < 24; ++oo) {
        feat2[base + (size_t)oo * 4096]  = accF[oo];
        value2[base + (size_t)oo * 4096] = __float2bfloat16(accV[oo]);
    }
}

// ---------------- K2: centers/sim/argmax (f64) + agg/dispatch (f32) ---------
__global__ __launch_bounds__(512) void k2_cluster(
    const double* __restrict__ feat2, const __hip_bfloat16* __restrict__ value2,
    const float* __restrict__ alpha_p, const float* __restrict__ beta_p,
    float* __restrict__ pre)
{
    __shared__ double chat[8][24];
    __shared__ float vcent[8][24];
    __shared__ float aggs[8][26];
    __shared__ float sums[8][8][24];  // per-wave copies
    __shared__ float cnts[8][8];
    __shared__ float s_lds[4096];
    __shared__ unsigned char m_lds[4096];

    const int B2 = blockIdx.x;
    const int t = threadIdx.x;
    const double* fB = feat2 + (size_t)B2 * 24 * 4096;
    const __hip_bfloat16* vB = value2 + (size_t)B2 * 24 * 4096;

    for (int k = t; k < 8 * 8 * 24; k += 512) ((float*)sums)[k] = 0.f;
    if (t < 64) ((float*)cnts)[t] = 0.f;

    // phase 1: block means (centers f64 / value_centers f32), one wave per m
    {
        const int m = t >> 6;
        const int j = t & 63;
        const int nbase = ((m >> 2) & 1) * 2048 + ((m >> 1) & 1) * 128 + (m & 1) * 8;
        double cF[24];
        float  cV[24];
        #pragma unroll
        for (int c = 0; c < 24; ++c) { cF[c] = 0.0; cV[c] = 0.f; }
        for (int k = 0; k < 8; ++k) {
            int q = j + k * 64;
            int n = nbase + (q >> 6) * 256 + ((q >> 3) & 7) * 16 + (q & 7);
            #pragma unroll
            for (int c = 0; c < 24; ++c) {
                cF[c] += fB[(size_t)c * 4096 + n];
                cV[c] += __bfloat162float(vB[(size_t)c * 4096 + n]);
            }
        }
        #pragma unroll
        for (int c = 0; c < 24; ++c) {
            #pragma unroll
            for (int off = 32; off >= 1; off >>= 1) {
                cF[c] += __shfl_down(cF[c], off, 64);
                cV[c] += __shfl_down(cV[c], off, 64);
            }
        }
        if (j == 0) {
            #pragma unroll
            for (int c = 0; c < 24; ++c) {
                chat[m][c]  = cF[c] * (1.0 / 512.0);
                vcent[m][c] = cV[c] * (1.f / 512.f);
            }
        }
    }
    __syncthreads();
    if (t < 8) {   // normalize centers in f64
        double ss = 0.0;
        #pragma unroll
        for (int c = 0; c < 24; ++c) ss += chat[t][c] * chat[t][c];
        double dn = fmax(sqrt(ss), 1e-12);
        #pragma unroll
        for (int c = 0; c < 24; ++c) chat[t][c] = chat[t][c] / dn;
    }
    __syncthreads();

    // phase 2: per-point f64 sim + first-argmax; f32 masked aggregation
    const double alpha = (double)alpha_p[0], beta = (double)beta_p[0];
    const int wv = t >> 6;
    for (int it = 0; it < 8; ++it) {
        const int n = it * 512 + t;
        double xn[24], ss = 0.0;
        #pragma unroll
        for (int c = 0; c < 24; ++c) { double u = fB[(size_t)c * 4096 + n]; xn[c] = u; ss += u * u; }
        const double dn = fmax(sqrt(ss), 1e-12);
        #pragma unroll
        for (int c = 0; c < 24; ++c) xn[c] = xn[c] / dn;

        double best = -1.0; int bm = 0;
        #pragma unroll
        for (int mm = 0; mm < 8; ++mm) {
            double d = 0.0;
            #pragma unroll
            for (int c4 = 0; c4 < 24; ++c4) d += chat[mm][c4] * xn[c4];
            double tv = beta + alpha * d;
            double sv = 1.0 / (1.0 + exp(-tv));
            if (sv > best) { best = sv; bm = mm; }
        }
        const float bestf = (float)best;
        s_lds[n] = bestf;
        m_lds[n] = (unsigned char)bm;
        #pragma unroll
        for (int c = 0; c < 24; ++c) {
            float v = __bfloat162float(vB[(size_t)c * 4096 + n]);
            atomicAdd(&sums[wv][bm][c], bestf * v);
        }
        atomicAdd(&cnts[wv][bm], bestf);
    }
    __syncthreads();

    // phase 3: agg = (sums + value_centers) / (cnt + 1)
    if (t < 192) {
        const int mm = t / 24, c = t % 24;
        float s8 = 0.f, c8 = 0.f;
        #pragma unroll
        for (int w = 0; w < 8; ++w) { s8 += sums[w][mm][c]; c8 += cnts[w][mm]; }
        aggs[mm][c] = (s8 + vcent[mm][c]) / (c8 + 1.f);
    }
    __syncthreads();

    // phase 4: dispatch + unfold + head-merge into pre (= d_out)
    const int b = B2 >> 5, e = (B2 >> 3) & 3;
    const int f1 = (B2 >> 2) & 1, f2 = (B2 >> 1) & 1, f3 = B2 & 1;
    float* preB = pre + ((size_t)b * 96 + e * 24) * 32768;
    const int sb = f1 * 16 * 1024 + f2 * 16 * 32 + f3 * 16;
    for (int it = 0; it < 8; ++it) {
        const int n = it * 512 + t;
        const float sbest = s_lds[n];
        const int bm = m_lds[n];
        const int s = sb + (n >> 8) * 1024 + ((n >> 4) & 15) * 32 + (n & 15);
        #pragma unroll
        for (int c = 0; c < 24; ++c)
            preB[(size_t)c * 32768 + s] = sbest * aggs[bm][c];
    }
}

// ---------------- K3: projection conv1x1, in-place on d_out -----------------
__global__ __launch_bounds__(256) void k3_proj(
    const float* __restrict__ wpT, const float* __restrict__ pb,
    float* __restrict__ io)
{
    __shared__ float xt[96][64];
    const int tile = blockIdx.x;
    const int b = tile >> 9;
    const int s0 = (tile & 511) << 6;
    float* xb = io + (size_t)b * 96 * 32768;

    #pragma unroll
    for (int k = 0; k < 24; ++k) {
        int idx = k * 256 + threadIdx.x;
        int c = idx >> 6, i = idx & 63;
        xt[c][i] = xb[(size_t)c * 32768 + s0 + i];
    }
    __syncthreads();

    const int i = threadIdx.x & 63;
    const int g = threadIdx.x >> 6;
    const int ob = __builtin_amdgcn_readfirstlane(g * 24);

    float acc[24];
    #pragma unroll
    for (int oo = 0; oo < 24; ++oo) acc[oo] = pb[ob + oo];

    for (int c = 0; c < 96; ++c) {
        float xv = xt[c][i];
        const float* wr = wpT + c * 96 + ob;
        #pragma unroll
        for (int oo = 0; oo < 24; ++oo) acc[oo] = fmaf(wr[oo], xv, acc[oo]);
    }
    #pragma unroll
    for (int oo = 0; oo < 24; ++oo)
        xb[(size_t)(ob + oo) * 32768 + s0 + i] = acc[oo];
}

// ---------------- launcher --------------------------------------------------
extern "C" void kernel_launch(void* const* d_in, const int* in_sizes, int n_in,
                              void* d_out, int out_size, void* d_ws, size_t ws_size,
                              hipStream_t stream)
{
    const float* x  = (const float*)d_in[0];
    const float* fw = (const float*)d_in[1];
    const float* fb = (const float*)d_in[2];
    const float* vw = (const float*)d_in[3];
    const float* vb = (const float*)d_in[4];
    const float* pw = (const float*)d_in[5];
    const float* pb = (const float*)d_in[6];
    const float* al = (const float*)d_in[7];
    const float* be = (const float*)d_in[8];
    float* out = (float*)d_out;

    char* ws = (char*)d_ws;
    double* wfdT = (double*)ws;                                 //    73728 B
    float*  wvT  = (float*)(ws + 73728);                        //    36864 B
    float*  wpT  = (float*)(ws + 110592);                       //    36864 B
    double* feat2 = (double*)(ws + 147456);                     // 100663296 B (f64)
    __hip_bfloat16* value2 =
        (__hip_bfloat16*)(ws + 147456 + 100663296);             //  25165824 B (bf16)
    // total workspace: ~126 MB

    k0_prep<<<36, 256, 0, stream>>>(fw, vw, pw, wfdT, wvT, wpT);
    k1_conv_fv<<<2048, 256, 0, stream>>>(x, wfdT, wvT, fb, vb, feat2, value2);
    k2_cluster<<<128, 512, 0, stream>>>(feat2, value2, al, be, out);
    k3_proj<<<2048, 256, 0, stream>>>(wpT, pb, out);
}

// Round 5
// 323.196 us; speedup vs baseline: 1.5136x; 1.5136x over previous
//
#include <hip/hip_runtime.h>
#include <hip/hip_bf16.h>

// B=4, C=96, vol 32^3; HEADS=4, HDIM=24, FOLD=2, PROP=2.
// 128 cluster batches (B2), each c=24, N=4096 points, M=8 centers.
// Argmax chain in f64 (matches np ref); everything else f32/bf16.
//
// Pipeline:
//  k0_prep  : weight transposes (f64 feat, f32 value/proj)
//  k_pool   : xmean[b][fold][m][c] f64 (pool(conv(x)) == conv(pool(x)))
//  k_cent   : chat (normalized centers, f64) + vcent f32 + zero sums/cnt
//  k1_conv  : f64 feat conv + f32 value conv + 8 dots + argmax + sv (fused)
//  k_agg    : masked aggregation -> global sums/cnt (LDS reduce + atomics)
//  k_disp   : agg finalize + dispatch + unfold + projection -> d_out

// ---------------- K0 --------------------------------------------------------
__global__ __launch_bounds__(256) void k0_prep(
    const float* __restrict__ fw, const float* __restrict__ vw,
    const float* __restrict__ pw, double* __restrict__ wfdT,
    float* __restrict__ wvT, float* __restrict__ wpT)
{
    int t = blockIdx.x * 256 + threadIdx.x;
    if (t < 96 * 96) {
        int o = t / 96, c = t % 96;
        wfdT[c * 96 + o] = (double)fw[o * 96 + c];
        wvT[c * 96 + o]  = vw[o * 96 + c];
        wpT[c * 96 + o]  = pw[o * 96 + c];
    }
}

// ---------------- K_pool: per-octant spatial means of x (f64) ---------------
// grid 96 x 256: gid -> (b,c) x (f1,f2,f3,m); each thread sums 512 x-values.
__global__ __launch_bounds__(256) void k_pool(
    const float* __restrict__ x, double* __restrict__ xmeanD)
{
    int gid = blockIdx.x * 256 + threadIdx.x;      // 24576 total
    int bc = gid >> 6;
    int b = bc / 96, c = bc - b * 96;
    int fm = gid & 63;
    int f1 = (fm >> 5) & 1, f2 = (fm >> 4) & 1, f3 = (fm >> 3) & 1, m = fm & 7;
    int W0 = f1 * 16 + (m >> 2) * 8;
    int H0 = f2 * 16 + ((m >> 1) & 1) * 8;
    int D0 = f3 * 16 + (m & 1) * 8;
    const float* xb = x + ((size_t)b * 96 + c) * 32768;
    double s = 0.0;
    for (int iw = 0; iw < 8; ++iw)
        for (int ih = 0; ih < 8; ++ih) {
            const float4* p = (const float4*)(xb + (W0 + iw) * 1024 + (H0 + ih) * 32 + D0);
            float4 a = p[0], q = p[1];
            s += (double)a.x + (double)a.y + (double)a.z + (double)a.w
               + (double)q.x + (double)q.y + (double)q.z + (double)q.w;
        }
    // grp = b*64 + fm : [b][f1][f2][f3][m]
    xmeanD[(size_t)(b * 64 + fm) * 96 + c] = s * (1.0 / 512.0);
}

// ---------------- K_cent: centers (f64) + vcent (f32) + zero sums -----------
// grid 128 x 192: thread (mm, co) of cluster batch B2.
__global__ __launch_bounds__(192) void k_cent(
    const float* __restrict__ fw, const float* __restrict__ fb,
    const float* __restrict__ vw, const float* __restrict__ vb,
    const double* __restrict__ xmeanD, double* __restrict__ chat,
    float* __restrict__ vcent, float* __restrict__ sums, float* __restrict__ cnt)
{
    __shared__ double centL[8][24];
    __shared__ double dnv[8];
    const int B2 = blockIdx.x, t = threadIdx.x;
    const int mm = t / 24, co = t - mm * 24;
    const int b = B2 >> 5, g = (B2 >> 3) & 3, fff = B2 & 7;
    const int ob = g * 24;
    const double* xm = xmeanD + (size_t)(b * 64 + fff * 8 + mm) * 96;
    double cF = (double)fb[ob + co];
    float  cV = vb[ob + co];
    const float* fr = fw + (ob + co) * 96;
    const float* vr = vw + (ob + co) * 96;
    for (int ci = 0; ci < 96; ++ci) {
        double xv = xm[ci];
        cF += (double)fr[ci] * xv;
        cV += vr[ci] * (float)xv;
    }
    centL[mm][co] = cF;
    __syncthreads();
    if (t < 8) {
        double ss = 0.0;
        #pragma unroll
        for (int cc = 0; cc < 24; ++cc) ss += centL[t][cc] * centL[t][cc];
        dnv[t] = fmax(sqrt(ss), 1e-12);
    }
    __syncthreads();
    chat[(size_t)B2 * 192 + mm * 24 + co] = cF / dnv[mm];
    vcent[(size_t)B2 * 192 + t] = cV;
    sums[(size_t)B2 * 192 + t] = 0.f;
    if (t < 8) cnt[B2 * 8 + t] = 0.f;
}

// ---------------- K1: fused conv + sim dots + argmax + sv -------------------
// grid 2048 x 256 (64 pos x 4 heads).
__global__ __launch_bounds__(256) void k1_conv(
    const float* __restrict__ x, const double* __restrict__ wfdT,
    const float* __restrict__ wvT, const float* __restrict__ fb,
    const float* __restrict__ vb, const double* __restrict__ chat,
    const float* __restrict__ al, const float* __restrict__ be,
    __hip_bfloat16* __restrict__ value2, float* __restrict__ svb,
    unsigned char* __restrict__ bmb)
{
    __shared__ float xt[96][64];
    __shared__ double chat_l[8][8][24];    // [slot=(g<<1)|f3][m][c]
    const int tile = blockIdx.x;
    const int b = tile >> 9;
    const int s0 = (tile & 511) << 6;
    const float* xb = x + (size_t)b * 96 * 32768;

    #pragma unroll
    for (int k = 0; k < 24; ++k) {
        int idx = k * 256 + threadIdx.x;
        int c = idx >> 6, i = idx & 63;
        xt[c][i] = xb[(size_t)c * 32768 + s0 + i];
    }
    const int f1 = (s0 >> 14) & 1;   // W>>4
    const int f2 = (s0 >> 9) & 1;    // H0>>4 (H pair never straddles 15/16)
    for (int k = threadIdx.x; k < 1536; k += 256) {
        int slot = k / 192, rem = k - slot * 192;
        int g = slot >> 1, f3 = slot & 1;
        int B2 = (b << 5) | (g << 3) | (f1 << 2) | (f2 << 1) | f3;
        ((double*)chat_l)[k] = chat[(size_t)B2 * 192 + rem];
    }
    __syncthreads();

    const int i = threadIdx.x & 63;
    const int g = threadIdx.x >> 6;
    const int ob = __builtin_amdgcn_readfirstlane(g * 24);

    double accF[24];
    float  accV[24];
    #pragma unroll
    for (int oo = 0; oo < 24; ++oo) { accF[oo] = (double)fb[ob + oo]; accV[oo] = vb[ob + oo]; }

    for (int c = 0; c < 96; ++c) {
        float xv = xt[c][i];
        double xd = (double)xv;
        const double* wf = wfdT + c * 96 + ob;   // wave-uniform -> s_load
        const float*  wv = wvT  + c * 96 + ob;
        #pragma unroll
        for (int oo = 0; oo < 24; ++oo) {
            accF[oo] = fma(xd, wf[oo], accF[oo]);
            accV[oo] = fmaf(xv, wv[oo], accV[oo]);
        }
    }

    const int s = s0 + i;
    const int D = s & 31, H = (s >> 5) & 31, W = s >> 10;
    const int f3 = D >> 4;
    const int n = ((W & 15) << 8) | ((H & 15) << 4) | (D & 15);
    const int B2 = (b << 5) | (g << 3) | (f1 << 2) | (f2 << 1) | f3;
    const int slot = (g << 1) | f3;

    const size_t vbase = (size_t)B2 * 24 * 4096 + n;
    #pragma unroll
    for (int oo = 0; oo < 24; ++oo)
        value2[vbase + (size_t)oo * 4096] = __float2bfloat16(accV[oo]);

    double ss = 0.0;
    #pragma unroll
    for (int c = 0; c < 24; ++c) ss += accF[c] * accF[c];
    const double dn = fmax(sqrt(ss), 1e-12);

    const double alpha = (double)al[0], beta = (double)be[0];
    double dbest;
    {
        double d0 = 0.0;
        #pragma unroll
        for (int c = 0; c < 24; ++c) d0 += chat_l[slot][0][c] * accF[c];
        dbest = d0;
    }
    int bmv = 0;
    #pragma unroll
    for (int mm = 1; mm < 8; ++mm) {
        double d = 0.0;
        #pragma unroll
        for (int c = 0; c < 24; ++c) d += chat_l[slot][mm][c] * accF[c];
        bool better = (alpha > 0.0) ? (d > dbest) : ((alpha < 0.0) ? (d < dbest) : false);
        if (better) { dbest = d; bmv = mm; }
    }
    const double tv = beta + alpha * (dbest / dn);
    const float sv = 1.f / (1.f + expf(-(float)tv));
    svb[(size_t)B2 * 4096 + n] = sv;
    bmb[(size_t)B2 * 4096 + n] = (unsigned char)bmv;
}

// ---------------- K_agg: masked aggregation ---------------------------------
// grid 512 (= 128 B2 x 4 chunks) x 256 threads.
__global__ __launch_bounds__(256) void k_agg(
    const __hip_bfloat16* __restrict__ value2, const float* __restrict__ svb,
    const unsigned char* __restrict__ bmb, float* __restrict__ sums,
    float* __restrict__ cnt)
{
    __shared__ float lsum[8][24];
    __shared__ float lcnt[8];
    const int B2 = blockIdx.x >> 2, chunk = blockIdx.x & 3;
    const int t = threadIdx.x;
    if (t < 192) ((float*)lsum)[t] = 0.f;
    if (t < 8) lcnt[t] = 0.f;
    __syncthreads();
    for (int r = 0; r < 4; ++r) {
        const int n = chunk * 1024 + r * 256 + t;
        const float svv = svb[(size_t)B2 * 4096 + n];
        const int bmv = bmb[(size_t)B2 * 4096 + n];
        atomicAdd(&lcnt[bmv], svv);
        #pragma unroll
        for (int c = 0; c < 24; ++c) {
            float v = __bfloat162float(value2[((size_t)B2 * 24 + c) * 4096 + n]);
            atomicAdd(&lsum[bmv][c], svv * v);
        }
    }
    __syncthreads();
    if (t < 192) atomicAdd(&sums[(size_t)B2 * 192 + t], ((float*)lsum)[t]);
    if (t < 8) atomicAdd(&cnt[B2 * 8 + t], lcnt[t]);
}

// ---------------- K_disp: agg finalize + dispatch + unfold + projection -----
// grid 2048 x 256.
__global__ __launch_bounds__(256) void k_disp(
    const float* __restrict__ sums, const float* __restrict__ cnt,
    const float* __restrict__ vcent, const float* __restrict__ svb,
    const unsigned char* __restrict__ bmb, const float* __restrict__ wpT,
    const float* __restrict__ pb, float* __restrict__ out)
{
    __shared__ float xt[96][64];
    __shared__ float agg_l[8][8][24];     // [slot][m][c]
    const int tile = blockIdx.x;
    const int b = tile >> 9;
    const int s0 = (tile & 511) << 6;
    const int f1 = (s0 >> 14) & 1, f2 = (s0 >> 9) & 1;
    for (int k = threadIdx.x; k < 1536; k += 256) {
        int slot = k / 192, rem = k - slot * 192;
        int g = slot >> 1, f3 = slot & 1;
        int B2 = (b << 5) | (g << 3) | (f1 << 2) | (f2 << 1) | f3;
        int mm = rem / 24;
        ((float*)agg_l)[k] =
            (sums[(size_t)B2 * 192 + rem] + vcent[(size_t)B2 * 192 + rem]) /
            (cnt[B2 * 8 + mm] + 1.f);
    }
    __syncthreads();

    const int i = threadIdx.x & 63;
    const int g = threadIdx.x >> 6;
    const int s = s0 + i;
    const int D = s & 31, H = (s >> 5) & 31, W = s >> 10;
    const int f3 = D >> 4;
    const int n = ((W & 15) << 8) | ((H & 15) << 4) | (D & 15);
    const int B2 = (b << 5) | (g << 3) | (f1 << 2) | (f2 << 1) | f3;
    const int slot = (g << 1) | f3;
    const float svv = svb[(size_t)B2 * 4096 + n];
    const int bmv = bmb[(size_t)B2 * 4096 + n];
    #pragma unroll
    for (int c = 0; c < 24; ++c) xt[g * 24 + c][i] = svv * agg_l[slot][bmv][c];
    __syncthreads();

    const int ob = __builtin_amdgcn_readfirstlane(g * 24);
    float acc[24];
    #pragma unroll
    for (int oo = 0; oo < 24; ++oo) acc[oo] = pb[ob + oo];
    for (int c = 0; c < 96; ++c) {
        float xv = xt[c][i];
        const float* wr = wpT + c * 96 + ob;   // wave-uniform -> s_load
        #pragma unroll
        for (int oo = 0; oo < 24; ++oo) acc[oo] = fmaf(wr[oo], xv, acc[oo]);
    }
    #pragma unroll
    for (int oo = 0; oo < 24; ++oo)
        out[((size_t)b * 96 + ob + oo) * 32768 + s0 + i] = acc[oo];
}

// ---------------- launcher --------------------------------------------------
extern "C" void kernel_launch(void* const* d_in, const int* in_sizes, int n_in,
                              void* d_out, int out_size, void* d_ws, size_t ws_size,
                              hipStream_t stream)
{
    const float* x  = (const float*)d_in[0];
    const float* fw = (const float*)d_in[1];
    const float* fb = (const float*)d_in[2];
    const float* vw = (const float*)d_in[3];
    const float* vb = (const float*)d_in[4];
    const float* pw = (const float*)d_in[5];
    const float* pb = (const float*)d_in[6];
    const float* al = (const float*)d_in[7];
    const float* be = (const float*)d_in[8];
    float* out = (float*)d_out;

    char* ws = (char*)d_ws;
    double* wfdT  = (double*)(ws);                   //    73728 B
    float*  wvT   = (float*)(ws + 73728);            //    36864 B
    float*  wpT   = (float*)(ws + 110592);           //    36864 B
    double* xmeanD= (double*)(ws + 147456);          //   196608 B [256][96]
    double* chat  = (double*)(ws + 344064);          //   196608 B [128][8][24]
    float*  vcent = (float*)(ws + 540672);           //    98304 B
    float*  sums  = (float*)(ws + 638976);           //    98304 B
    float*  cnt   = (float*)(ws + 737280);           //     4096 B
    __hip_bfloat16* value2 = (__hip_bfloat16*)(ws + 741376);   // 25165824 B
    float*  svb   = (float*)(ws + 25907200);         //  2097152 B
    unsigned char* bmb = (unsigned char*)(ws + 28004352);      // 524288 B
    // total ~28.5 MB

    k0_prep<<<36, 256, 0, stream>>>(fw, vw, pw, wfdT, wvT, wpT);
    k_pool<<<96, 256, 0, stream>>>(x, xmeanD);
    k_cent<<<128, 192, 0, stream>>>(fw, fb, vw, vb, xmeanD, chat, vcent, sums, cnt);
    k1_conv<<<2048, 256, 0, stream>>>(x, wfdT, wvT, fb, vb, chat, al, be,
                                      value2, svb, bmb);
    k_agg<<<512, 256, 0, stream>>>(value2, svb, bmb, sums, cnt);
    k_disp<<<2048, 256, 0, stream>>>(sums, cnt, vcent, svb, bmb, wpT, pb, out);
}